// Round 8
// baseline (324.033 us; speedup 1.0000x reference)
//
#include <hip/hip_runtime.h>
#include <hip/hip_bf16.h>

#define D 128
#define CH 4096   // edges per block in CSR partition passes

typedef unsigned int u32;
typedef unsigned short u16;
typedef __attribute__((ext_vector_type(8))) short s16x8;
typedef __attribute__((ext_vector_type(4))) float f32x4;
typedef __attribute__((ext_vector_type(2))) float f32x2;
typedef __attribute__((ext_vector_type(2))) u32 u32x2;
typedef __attribute__((ext_vector_type(4))) u32 u32x4;

__device__ __forceinline__ float bf2f(u16 u) {
    union { u32 u; float f; } v; v.u = ((u32)u) << 16; return v.f;
}
__device__ __forceinline__ u16 f2bf(float f) {
    union { float f; u32 u; } v; v.f = f;
    return (u16)((v.u + 0x7fffu + ((v.u >> 16) & 1u)) >> 16);
}
__device__ __forceinline__ u32 pack_bf2(float a, float b) {
    __hip_bfloat162 t = __float22bfloat162_rn(make_float2(a, b));
    union { __hip_bfloat162 t; u32 u; } v; v.t = t; return v.u;
}
__device__ __forceinline__ void unpack2(u32 u, float& lo, float& hi) {
    union { u32 u; float f; } a, b;
    a.u = u << 16; b.u = u & 0xffff0000u;
    lo = a.f; hi = b.f;
}
__device__ __forceinline__ void acc8(float (&a)[8], u32x4 u) {
#pragma unroll
    for (int m = 0; m < 4; ++m) {
        float l, h;
        unpack2(u[m], l, h);
        a[2 * m] += l; a[2 * m + 1] += h;
    }
}

// ---- dtype detector (also zeroes gcnt for the CSR build) ----
__global__ void detect_dtype(const u16* __restrict__ x, int* __restrict__ flag,
                             int* __restrict__ gcnt, int nbuck) {
    __shared__ int cnt;
    if (threadIdx.x == 0) cnt = 0;
    __syncthreads();
    if ((int)threadIdx.x < nbuck) gcnt[threadIdx.x] = 0;
    u16 u = x[2 * threadIdx.x];
    int e = (u >> 7) & 0xFF;
    if (e >= 96 && e <= 150) atomicAdd(&cnt, 1);
    __syncthreads();
    if (threadIdx.x == 0) *flag = (cnt >= 128) ? 0 : 1;
}

// ---- canonicalize, grid-stride (body only runs when inputs are fp32) ----
__global__ __launch_bounds__(256)
void to_bf16_all(const void* __restrict__ s0, const void* __restrict__ s1,
                 const void* __restrict__ s2, const void* __restrict__ s3,
                 const void* __restrict__ s4, const void* __restrict__ s5,
                 const void* __restrict__ s6,
                 u16* __restrict__ d0, u16* __restrict__ d1, u16* __restrict__ d2,
                 u16* __restrict__ d3, u16* __restrict__ d4, u16* __restrict__ d5,
                 u16* __restrict__ d6,
                 long long n0, long long n1, long long n2, long long n3,
                 long long n4, long long n5, long long n6,
                 const int* __restrict__ flag)
{
    if (*flag == 0) return;
    long long tot = n0 + n1 + n2 + n3 + n4 + n5 + n6;
    long long stride = (long long)gridDim.x * 256;
    for (long long i = (long long)blockIdx.x * 256 + threadIdx.x; i < tot; i += stride) {
        const void* s; u16* d; long long off;
        if      (i < n0)                   { s = s0; d = d0; off = i; }
        else if (i < n0+n1)                { s = s1; d = d1; off = i-n0; }
        else if (i < n0+n1+n2)             { s = s2; d = d2; off = i-n0-n1; }
        else if (i < n0+n1+n2+n3)          { s = s3; d = d3; off = i-n0-n1-n2; }
        else if (i < n0+n1+n2+n3+n4)       { s = s4; d = d4; off = i-n0-n1-n2-n3; }
        else if (i < n0+n1+n2+n3+n4+n5)    { s = s5; d = d5; off = i-n0-n1-n2-n3-n4; }
        else                               { s = s6; d = d6; off = i-n0-n1-n2-n3-n4-n5; }
        d[off] = f2bf(((const float*)s)[off]);
    }
}

// ==== bucketed CSR build: bucket = dst>>8 (needs N<=65536, R*N<2^24) ====
__global__ __launch_bounds__(256)
void csr_count(const int* __restrict__ dst, int* __restrict__ gcnt, int E, int nbuck) {
    __shared__ int scnt[256];
    int tid = threadIdx.x;
    scnt[tid] = 0;
    __syncthreads();
    int base = blockIdx.x * CH;
#pragma unroll
    for (int it = 0; it < CH / 256; ++it) {
        int e = base + it * 256 + tid;
        if (e < E) atomicAdd(&scnt[dst[e] >> 8], 1);
    }
    __syncthreads();
    if (tid < nbuck && scnt[tid] > 0) atomicAdd(&gcnt[tid], scnt[tid]);
}

__global__ __launch_bounds__(256)
void csr_scan(const int* __restrict__ gcnt, int* __restrict__ bstart, int* __restrict__ bcur,
              int nbuck, int N_, int E_, int* __restrict__ offs) {
    __shared__ int wpart[4];
    int tid = threadIdx.x, lane = tid & 63, wid = tid >> 6;
    int v = (tid < nbuck) ? gcnt[tid] : 0;
    int s = v;
#pragma unroll
    for (int off = 1; off < 64; off <<= 1) {
        int t = __shfl_up(s, off, 64);
        if (lane >= off) s += t;
    }
    if (lane == 63) wpart[wid] = s;
    __syncthreads();
    int add = 0;
    for (int w = 0; w < wid; ++w) add += wpart[w];
    int excl = add + s - v;
    if (tid <= nbuck) bstart[tid] = excl;
    if (tid < nbuck)  bcur[tid]  = excl;
    if (tid == 0) offs[N_] = E_;
}

// partition edges into bucket-contiguous ebuf; rec = (dst&255)<<24 | (et*N+src)
__global__ __launch_bounds__(256)
void csr_part(const int* __restrict__ src, const int* __restrict__ dst,
              const int* __restrict__ et, int* __restrict__ bcur,
              u32* __restrict__ ebuf, int E, int N, int nbuck) {
    __shared__ int scnt[256], sbase[256];
    int tid = threadIdx.x;
    scnt[tid] = 0;
    __syncthreads();
    int base = blockIdx.x * CH;
#pragma unroll
    for (int it = 0; it < CH / 256; ++it) {
        int e = base + it * 256 + tid;
        if (e < E) atomicAdd(&scnt[dst[e] >> 8], 1);
    }
    __syncthreads();
    if (tid < nbuck) {
        int c = scnt[tid];
        sbase[tid] = c ? atomicAdd(&bcur[tid], c) : 0;
    }
    __syncthreads();
    scnt[tid] = 0;
    __syncthreads();
#pragma unroll
    for (int it = 0; it < CH / 256; ++it) {
        int e = base + it * 256 + tid;
        if (e >= E) continue;
        int d = dst[e];
        int b = d >> 8;
        int p = sbase[b] + atomicAdd(&scnt[b], 1);
        ebuf[p] = ((u32)(d & 255) << 24) | (u32)(et[e] * N + src[e]);
    }
}

// one block per bucket: 256-bin dstlo counting sort -> offs + rowidx
__global__ __launch_bounds__(256)
void csr_emit(const u32* __restrict__ ebuf, const int* __restrict__ bstart,
              int* __restrict__ offs, int* __restrict__ rowidx, int N) {
    __shared__ int hist[256], excl[256], cur[256];
    __shared__ int wpart[4];
    int b = blockIdx.x, tid = threadIdx.x;
    int lo = bstart[b], hi = bstart[b + 1];
    hist[tid] = 0; cur[tid] = 0;
    __syncthreads();
    for (int i = lo + tid; i < hi; i += 256) atomicAdd(&hist[ebuf[i] >> 24], 1);
    __syncthreads();
    int lane = tid & 63, wid = tid >> 6;
    int v = hist[tid], s = v;
#pragma unroll
    for (int off = 1; off < 64; off <<= 1) {
        int t = __shfl_up(s, off, 64);
        if (lane >= off) s += t;
    }
    if (lane == 63) wpart[wid] = s;
    __syncthreads();
    int add = 0;
    for (int w = 0; w < wid; ++w) add += wpart[w];
    int e_ = add + s - v;
    excl[tid] = e_;
    int node = (b << 8) + tid;
    if (node < N) offs[node] = lo + e_;
    __syncthreads();
    for (int i = lo + tid; i < hi; i += 256) {
        u32 rec = ebuf[i];
        int dl = rec >> 24;
        int p = lo + excl[dl] + atomicAdd(&cur[dl], 1);
        rowidx[p] = (int)(rec & 0xFFFFFFu);
    }
}

// ---- GEMM: C[M,128] = A @ B ; LDS-staged A, nt stores (keep A resident in L3) ----
__global__ __launch_bounds__(256)
void gemm_k128(const u16* __restrict__ Ac, const u16* __restrict__ Ao,
               const u16* __restrict__ Wc, const u16* __restrict__ Wo,
               const u16* __restrict__ lWc, const u16* __restrict__ lWo,
               const u16* __restrict__ bc, const u16* __restrict__ bo,
               const int* __restrict__ flag,
               int M, int R_, u16* __restrict__ xw, u16* __restrict__ sl)
{
    __shared__ u16 As[128 * 128];
    const bool f = (*flag != 0);
    const u16* A     = f ? Ac  : Ao;
    const u16* Wall  = f ? Wc  : Wo;
    const u16* loopW = f ? lWc : lWo;
    const u16* bias  = f ? bc  : bo;

    const int y = blockIdx.y;
    const u16* B = (y < R_) ? (Wall + (long long)y * D * D) : loopW;
    const int row0 = blockIdx.x * 128;
    const int tid  = threadIdx.x;
    const int lane = tid & 63;
    const int wv   = tid >> 6;
    const int quad = lane >> 4;
    const int l16  = lane & 15;

    {
        int r_base = (wv << 2) + (lane >> 4);
        int c      = lane & 15;
        auto* lds0 = (__attribute__((address_space(3))) char*)As;
#pragma unroll
        for (int it = 0; it < 8; ++it) {
            int rl = it * 16 + r_base;
            int cg = c ^ (rl & 15);
            int rg = row0 + rl; if (rg >= M) rg = M - 1;
            const u16* gp = A + (long long)rg * D + cg * 8;
            __builtin_amdgcn_global_load_lds(
                (const __attribute__((address_space(1))) void*)gp,
                (__attribute__((address_space(3))) void*)(lds0 + it * 4096 + wv * 1024),
                16, 0, 0);
        }
    }

    s16x8 bf[4][2];
#pragma unroll
    for (int kk = 0; kk < 4; ++kk)
#pragma unroll
        for (int j = 0; j < 8; ++j) {
            u32 p = *(const u32*)(B + (kk * 32 + quad * 8 + j) * D + wv * 32 + 2 * l16);
            bf[kk][0][j] = (short)(p & 0xffffu);
            bf[kk][1][j] = (short)(p >> 16);
        }

    f32x4 acc[8][2];
#pragma unroll
    for (int mt = 0; mt < 8; ++mt) { acc[mt][0] = (f32x4)0.f; acc[mt][1] = (f32x4)0.f; }

    __syncthreads();

#pragma unroll
    for (int kk = 0; kk < 4; ++kk) {
        const int chunk = (kk * 4 + quad) ^ l16;
#pragma unroll
        for (int mt = 0; mt < 8; ++mt) {
            int rl = mt * 16 + l16;
            s16x8 a = *(const s16x8*)(As + rl * D + chunk * 8);
            acc[mt][0] = __builtin_amdgcn_mfma_f32_16x16x32_bf16(a, bf[kk][0], acc[mt][0], 0, 0, 0);
            acc[mt][1] = __builtin_amdgcn_mfma_f32_16x16x32_bf16(a, bf[kk][1], acc[mt][1], 0, 0, 0);
        }
    }

    long long MD64 = (long long)M * 64;
    int cpair = wv * 16 + l16;
    if (y < R_) {
        u32* o = (u32*)xw + (long long)y * MD64;
#pragma unroll
        for (int mt = 0; mt < 8; ++mt)
#pragma unroll
            for (int i = 0; i < 4; ++i) {
                int r = row0 + mt * 16 + quad * 4 + i;
                if (r >= M) continue;
                __builtin_nontemporal_store(pack_bf2(acc[mt][0][i], acc[mt][1][i]),
                                            &o[(long long)r * 64 + cpair]);
            }
    } else {
        float b0 = bf2f(bias[wv * 32 + 2 * l16]);
        float b1 = bf2f(bias[wv * 32 + 2 * l16 + 1]);
        u32* o = (u32*)sl;
#pragma unroll
        for (int mt = 0; mt < 8; ++mt)
#pragma unroll
            for (int i = 0; i < 4; ++i) {
                int r = row0 + mt * 16 + quad * 4 + i;
                if (r >= M) continue;
                __builtin_nontemporal_store(pack_bf2(acc[mt][0][i] + b0, acc[mt][1][i] + b1),
                                            &o[(long long)r * 64 + cpair]);
            }
    }
}

// ---- aggregate v3: one wave per dst node; quarter-wave (16 lanes) per edge row ----
// lane = qw*16 + p : handles row (j + qw), u32x4 index p (features 8p..8p+7)
// main loop: 4 load instrs / lane cover 16 edges (16 rows in flight per wave)
__global__ __launch_bounds__(256)
void aggregate(const u16* __restrict__ xw, const u16* __restrict__ sl,
               const int* __restrict__ offs, const int* __restrict__ rowidx,
               void* __restrict__ out, int N, int mode, const int* __restrict__ flag)
{
    int node = blockIdx.x * 4 + (threadIdx.x >> 6);
    int lane = threadIdx.x & 63;
    int p  = lane & 15;
    int qw = lane >> 4;
    if (node >= N) return;
    const u32x4* xw4 = (const u32x4*)xw;   // row stride = 16 u32x4

    float a[8];
    if (qw == 0) {
        u32x4 s4 = ((const u32x4*)sl)[(long long)node * 16 + p];
#pragma unroll
        for (int m = 0; m < 4; ++m) unpack2(s4[m], a[2 * m], a[2 * m + 1]);
    } else {
#pragma unroll
        for (int k = 0; k < 8; ++k) a[k] = 0.f;
    }

    int j = offs[node], j1 = offs[node + 1];
    for (; j + 16 <= j1; j += 16) {
        int r0 = rowidx[j + qw];
        int r1 = rowidx[j + 4 + qw];
        int r2 = rowidx[j + 8 + qw];
        int r3 = rowidx[j + 12 + qw];
        u32x4 u0 = xw4[(long long)r0 * 16 + p];
        u32x4 u1 = xw4[(long long)r1 * 16 + p];
        u32x4 u2 = xw4[(long long)r2 * 16 + p];
        u32x4 u3 = xw4[(long long)r3 * 16 + p];
        acc8(a, u0); acc8(a, u1); acc8(a, u2); acc8(a, u3);
    }
    for (; j + 4 <= j1; j += 4) {
        int r = rowidx[j + qw];
        acc8(a, xw4[(long long)r * 16 + p]);
    }
    int rem = j1 - j;
    if (rem > 0) {
        int rr = rowidx[(qw < rem) ? j + qw : j];
        u32x4 u = xw4[(long long)rr * 16 + p];
        if (qw >= rem) { u[0] = 0; u[1] = 0; u[2] = 0; u[3] = 0; }
        acc8(a, u);
    }

    // combine the four quarter-wave partials
#pragma unroll
    for (int k = 0; k < 8; ++k) {
        a[k] += __shfl_xor(a[k], 16, 64);
        a[k] += __shfl_xor(a[k], 32, 64);
    }

    if (mode == 0) {
        if (qw == 0) {
            u32x4 w;
#pragma unroll
            for (int m = 0; m < 4; ++m)
                w[m] = pack_bf2(fmaxf(a[2 * m], 0.f), fmaxf(a[2 * m + 1], 0.f));
            __builtin_nontemporal_store(w, &((u32x4*)out)[(long long)node * 16 + p]);
        }
    } else {
        float s = 0.f;
#pragma unroll
        for (int k = 0; k < 8; ++k) s += a[k] * a[k];
#pragma unroll
        for (int off = 8; off > 0; off >>= 1) s += __shfl_xor(s, off, 64);
        float sc = 1.f / fmaxf(sqrtf(s), 1e-12f);
        if (qw == 0) {
            if (*flag) {
                f32x4 w0, w1;
#pragma unroll
                for (int m = 0; m < 4; ++m) {
                    float* wp = (m < 2) ? (float*)&w0 : (float*)&w1;
                    wp[(m & 1) * 2]     = a[2 * m] * sc;
                    wp[(m & 1) * 2 + 1] = a[2 * m + 1] * sc;
                }
                __builtin_nontemporal_store(w0, &((f32x4*)out)[(long long)node * 32 + p * 2]);
                __builtin_nontemporal_store(w1, &((f32x4*)out)[(long long)node * 32 + p * 2 + 1]);
            } else {
                u32x4 w;
#pragma unroll
                for (int m = 0; m < 4; ++m)
                    w[m] = pack_bf2(a[2 * m] * sc, a[2 * m + 1] * sc);
                __builtin_nontemporal_store(w, &((u32x4*)out)[(long long)node * 16 + p]);
            }
        }
    }
}

static inline size_t align256(size_t x) { return (x + 255) & ~(size_t)255; }

extern "C" void kernel_launch(void* const* d_in, const int* in_sizes, int n_in,
                              void* d_out, int out_size, void* d_ws, size_t ws_size,
                              hipStream_t stream)
{
    const void* x_in   = d_in[0];
    const void* W1_in  = d_in[1];
    const void* lW1_in = d_in[2];
    const void* b1_in  = d_in[3];
    const void* W2_in  = d_in[4];
    const void* lW2_in = d_in[5];
    const void* b2_in  = d_in[6];
    const int* src = (const int*)d_in[7];
    const int* dst = (const int*)d_in[8];
    const int* et  = (const int*)d_in[9];

    const int N = in_sizes[0] / D;            // 50000
    const int E = in_sizes[7];                // 800000
    const int R = in_sizes[1] / (D * D);      // 8
    const int nbuck = (N + 255) >> 8;         // 196

    const long long ND  = (long long)N * D;
    const long long RDD = (long long)R * D * D;
    const long long DDl = (long long)D * D;

    size_t off = 0;
    auto alloc = [&](size_t bytes) { size_t o = off; off = align256(off + bytes); return o; };
    size_t o_flag = alloc(256);
    size_t o_xc   = alloc((size_t)ND * 2);
    size_t o_W1   = alloc((size_t)RDD * 2);
    size_t o_lW1  = alloc((size_t)DDl * 2);
    size_t o_b1   = alloc((size_t)D * 2);
    size_t o_W2   = alloc((size_t)RDD * 2);
    size_t o_lW2  = alloc((size_t)DDl * 2);
    size_t o_b2   = alloc((size_t)D * 2);
    size_t o_sl   = alloc((size_t)ND * 2);
    size_t o_h    = alloc((size_t)ND * 2);
    size_t o_offs = alloc((size_t)(N + 1) * 4);
    size_t o_gcnt = alloc(1024);
    size_t o_bst  = alloc(1040 * 4);
    size_t o_bcur = alloc(1024);
    size_t o_ebuf = alloc((size_t)E * 4);
    size_t o_ridx = alloc((size_t)E * 4);
    size_t o_xw   = alloc((size_t)R * ND * 2);
    (void)ws_size;

    char* ws = (char*)d_ws;
    int* flag   = (int*)(ws + o_flag);
    u16* x_c    = (u16*)(ws + o_xc);
    u16* W1c    = (u16*)(ws + o_W1);
    u16* lW1c   = (u16*)(ws + o_lW1);
    u16* b1c    = (u16*)(ws + o_b1);
    u16* W2c    = (u16*)(ws + o_W2);
    u16* lW2c   = (u16*)(ws + o_lW2);
    u16* b2c    = (u16*)(ws + o_b2);
    u16* sl     = (u16*)(ws + o_sl);
    u16* h      = (u16*)(ws + o_h);
    int* offs   = (int*)(ws + o_offs);
    int* gcnt   = (int*)(ws + o_gcnt);
    int* bstart = (int*)(ws + o_bst);
    int* bcur   = (int*)(ws + o_bcur);
    u32* ebuf   = (u32*)(ws + o_ebuf);
    int* rowidx = (int*)(ws + o_ridx);
    u16* xw     = (u16*)(ws + o_xw);

    dim3 blk(256, 1, 1);
    int mb    = (N + 127) / 128;
    int nblkE = (E + CH - 1) / CH;

    detect_dtype<<<dim3(1), blk, 0, stream>>>((const u16*)x_in, flag, gcnt, nbuck);
    to_bf16_all<<<dim3(4096), blk, 0, stream>>>(
        x_in, W1_in, lW1_in, b1_in, W2_in, lW2_in, b2_in,
        x_c, W1c, lW1c, b1c, W2c, lW2c, b2c,
        ND, RDD, DDl, (long long)D, RDD, DDl, (long long)D, flag);

    // CSR build (bucketed counting sort)
    csr_count<<<dim3(nblkE), blk, 0, stream>>>(dst, gcnt, E, nbuck);
    csr_scan<<<dim3(1), blk, 0, stream>>>(gcnt, bstart, bcur, nbuck, N, E, offs);
    csr_part<<<dim3(nblkE), blk, 0, stream>>>(src, dst, et, bcur, ebuf, E, N, nbuck);
    csr_emit<<<dim3(nbuck), blk, 0, stream>>>(ebuf, bstart, offs, rowidx, N);

    // layer 1
    gemm_k128<<<dim3(mb, R + 1), blk, 0, stream>>>(
        x_c, (const u16*)x_in, W1c, (const u16*)W1_in, lW1c, (const u16*)lW1_in,
        b1c, (const u16*)b1_in, flag, N, R, xw, sl);
    aggregate<<<dim3((N + 3) / 4), blk, 0, stream>>>(xw, sl, offs, rowidx, h, N, 0, flag);

    // layer 2
    gemm_k128<<<dim3(mb, R + 1), blk, 0, stream>>>(
        h, h, W2c, (const u16*)W2_in, lW2c, (const u16*)lW2_in,
        b2c, (const u16*)b2_in, flag, N, R, xw, sl);
    aggregate<<<dim3((N + 3) / 4), blk, 0, stream>>>(xw, sl, offs, rowidx, d_out, N, 1, flag);
}

// Round 9
// 305.559 us; speedup vs baseline: 1.0605x; 1.0605x over previous
//
#include <hip/hip_runtime.h>
#include <hip/hip_bf16.h>

#define D 128
#define CH 4096   // edges per block in CSR partition passes

typedef unsigned int u32;
typedef unsigned short u16;
typedef __attribute__((ext_vector_type(8))) short s16x8;
typedef __attribute__((ext_vector_type(4))) float f32x4;
typedef __attribute__((ext_vector_type(2))) float f32x2;
typedef __attribute__((ext_vector_type(2))) u32 u32x2;
typedef __attribute__((ext_vector_type(4))) u32 u32x4;

__device__ __forceinline__ float bf2f(u16 u) {
    union { u32 u; float f; } v; v.u = ((u32)u) << 16; return v.f;
}
__device__ __forceinline__ u16 f2bf(float f) {
    union { float f; u32 u; } v; v.f = f;
    return (u16)((v.u + 0x7fffu + ((v.u >> 16) & 1u)) >> 16);
}
__device__ __forceinline__ u32 pack_bf2(float a, float b) {
    __hip_bfloat162 t = __float22bfloat162_rn(make_float2(a, b));
    union { __hip_bfloat162 t; u32 u; } v; v.t = t; return v.u;
}
__device__ __forceinline__ void unpack2(u32 u, float& lo, float& hi) {
    union { u32 u; float f; } a, b;
    a.u = u << 16; b.u = u & 0xffff0000u;
    lo = a.f; hi = b.f;
}

// ---- dtype detector (also zeroes gcnt for the CSR build) ----
__global__ void detect_dtype(const u16* __restrict__ x, int* __restrict__ flag,
                             int* __restrict__ gcnt, int nbuck) {
    __shared__ int cnt;
    if (threadIdx.x == 0) cnt = 0;
    __syncthreads();
    if ((int)threadIdx.x < nbuck) gcnt[threadIdx.x] = 0;
    u16 u = x[2 * threadIdx.x];
    int e = (u >> 7) & 0xFF;
    if (e >= 96 && e <= 150) atomicAdd(&cnt, 1);
    __syncthreads();
    if (threadIdx.x == 0) *flag = (cnt >= 128) ? 0 : 1;
}

// ---- canonicalize, grid-stride (body only runs when inputs are fp32) ----
__global__ __launch_bounds__(256)
void to_bf16_all(const void* __restrict__ s0, const void* __restrict__ s1,
                 const void* __restrict__ s2, const void* __restrict__ s3,
                 const void* __restrict__ s4, const void* __restrict__ s5,
                 const void* __restrict__ s6,
                 u16* __restrict__ d0, u16* __restrict__ d1, u16* __restrict__ d2,
                 u16* __restrict__ d3, u16* __restrict__ d4, u16* __restrict__ d5,
                 u16* __restrict__ d6,
                 long long n0, long long n1, long long n2, long long n3,
                 long long n4, long long n5, long long n6,
                 const int* __restrict__ flag)
{
    if (*flag == 0) return;
    long long tot = n0 + n1 + n2 + n3 + n4 + n5 + n6;
    long long stride = (long long)gridDim.x * 256;
    for (long long i = (long long)blockIdx.x * 256 + threadIdx.x; i < tot; i += stride) {
        const void* s; u16* d; long long off;
        if      (i < n0)                   { s = s0; d = d0; off = i; }
        else if (i < n0+n1)                { s = s1; d = d1; off = i-n0; }
        else if (i < n0+n1+n2)             { s = s2; d = d2; off = i-n0-n1; }
        else if (i < n0+n1+n2+n3)          { s = s3; d = d3; off = i-n0-n1-n2; }
        else if (i < n0+n1+n2+n3+n4)       { s = s4; d = d4; off = i-n0-n1-n2-n3; }
        else if (i < n0+n1+n2+n3+n4+n5)    { s = s5; d = d5; off = i-n0-n1-n2-n3-n4; }
        else                               { s = s6; d = d6; off = i-n0-n1-n2-n3-n4-n5; }
        d[off] = f2bf(((const float*)s)[off]);
    }
}

// ==== bucketed CSR build: bucket = dst>>8 (needs N<=65536, R*N<2^24) ====
__global__ __launch_bounds__(256)
void csr_count(const int* __restrict__ dst, int* __restrict__ gcnt, int E, int nbuck) {
    __shared__ int scnt[256];
    int tid = threadIdx.x;
    scnt[tid] = 0;
    __syncthreads();
    int base = blockIdx.x * CH;
#pragma unroll
    for (int it = 0; it < CH / 256; ++it) {
        int e = base + it * 256 + tid;
        if (e < E) atomicAdd(&scnt[dst[e] >> 8], 1);
    }
    __syncthreads();
    if (tid < nbuck && scnt[tid] > 0) atomicAdd(&gcnt[tid], scnt[tid]);
}

__global__ __launch_bounds__(256)
void csr_scan(const int* __restrict__ gcnt, int* __restrict__ bstart, int* __restrict__ bcur,
              int nbuck, int N_, int E_, int* __restrict__ offs) {
    __shared__ int wpart[4];
    int tid = threadIdx.x, lane = tid & 63, wid = tid >> 6;
    int v = (tid < nbuck) ? gcnt[tid] : 0;
    int s = v;
#pragma unroll
    for (int off = 1; off < 64; off <<= 1) {
        int t = __shfl_up(s, off, 64);
        if (lane >= off) s += t;
    }
    if (lane == 63) wpart[wid] = s;
    __syncthreads();
    int add = 0;
    for (int w = 0; w < wid; ++w) add += wpart[w];
    int excl = add + s - v;
    if (tid <= nbuck) bstart[tid] = excl;
    if (tid < nbuck)  bcur[tid]  = excl;
    if (tid == 0) offs[N_] = E_;
}

// partition edges into bucket-contiguous ebuf; rec = (dst&255)<<24 | (et*N+src)
__global__ __launch_bounds__(256)
void csr_part(const int* __restrict__ src, const int* __restrict__ dst,
              const int* __restrict__ et, int* __restrict__ bcur,
              u32* __restrict__ ebuf, int E, int N, int nbuck) {
    __shared__ int scnt[256], sbase[256];
    int tid = threadIdx.x;
    scnt[tid] = 0;
    __syncthreads();
    int base = blockIdx.x * CH;
#pragma unroll
    for (int it = 0; it < CH / 256; ++it) {
        int e = base + it * 256 + tid;
        if (e < E) atomicAdd(&scnt[dst[e] >> 8], 1);
    }
    __syncthreads();
    if (tid < nbuck) {
        int c = scnt[tid];
        sbase[tid] = c ? atomicAdd(&bcur[tid], c) : 0;
    }
    __syncthreads();
    scnt[tid] = 0;
    __syncthreads();
#pragma unroll
    for (int it = 0; it < CH / 256; ++it) {
        int e = base + it * 256 + tid;
        if (e >= E) continue;
        int d = dst[e];
        int b = d >> 8;
        int p = sbase[b] + atomicAdd(&scnt[b], 1);
        ebuf[p] = ((u32)(d & 255) << 24) | (u32)(et[e] * N + src[e]);
    }
}

// one block per bucket: 256-bin dstlo counting sort -> offs + rowidx
__global__ __launch_bounds__(256)
void csr_emit(const u32* __restrict__ ebuf, const int* __restrict__ bstart,
              int* __restrict__ offs, int* __restrict__ rowidx, int N) {
    __shared__ int hist[256], excl[256], cur[256];
    __shared__ int wpart[4];
    int b = blockIdx.x, tid = threadIdx.x;
    int lo = bstart[b], hi = bstart[b + 1];
    hist[tid] = 0; cur[tid] = 0;
    __syncthreads();
    for (int i = lo + tid; i < hi; i += 256) atomicAdd(&hist[ebuf[i] >> 24], 1);
    __syncthreads();
    int lane = tid & 63, wid = tid >> 6;
    int v = hist[tid], s = v;
#pragma unroll
    for (int off = 1; off < 64; off <<= 1) {
        int t = __shfl_up(s, off, 64);
        if (lane >= off) s += t;
    }
    if (lane == 63) wpart[wid] = s;
    __syncthreads();
    int add = 0;
    for (int w = 0; w < wid; ++w) add += wpart[w];
    int e_ = add + s - v;
    excl[tid] = e_;
    int node = (b << 8) + tid;
    if (node < N) offs[node] = lo + e_;
    __syncthreads();
    for (int i = lo + tid; i < hi; i += 256) {
        u32 rec = ebuf[i];
        int dl = rec >> 24;
        int p = lo + excl[dl] + atomicAdd(&cur[dl], 1);
        rowidx[p] = (int)(rec & 0xFFFFFFu);
    }
}

// ---- GEMM: C[M,128] = A @ B ; LDS-staged A; LDS-transposed epilogue so every
// ---- global store instr writes 1 KB contiguous (8 full 128B lines, no RMW) ----
__global__ __launch_bounds__(256)
void gemm_k128(const u16* __restrict__ Ac, const u16* __restrict__ Ao,
               const u16* __restrict__ Wc, const u16* __restrict__ Wo,
               const u16* __restrict__ lWc, const u16* __restrict__ lWo,
               const u16* __restrict__ bc, const u16* __restrict__ bo,
               const int* __restrict__ flag,
               int M, int R_, u16* __restrict__ xw, u16* __restrict__ sl)
{
    __shared__ u16 As[128 * 128];    // 32 KB; reused as C staging (128 rows x 64 u32)
    const bool f = (*flag != 0);
    const u16* A     = f ? Ac  : Ao;
    const u16* Wall  = f ? Wc  : Wo;
    const u16* loopW = f ? lWc : lWo;
    const u16* bias  = f ? bc  : bo;

    const int y = blockIdx.y;
    const u16* B = (y < R_) ? (Wall + (long long)y * D * D) : loopW;
    const int row0 = blockIdx.x * 128;
    const int tid  = threadIdx.x;
    const int lane = tid & 63;
    const int wv   = tid >> 6;
    const int quad = lane >> 4;
    const int l16  = lane & 15;

    {
        int r_base = (wv << 2) + (lane >> 4);
        int c      = lane & 15;
        auto* lds0 = (__attribute__((address_space(3))) char*)As;
#pragma unroll
        for (int it = 0; it < 8; ++it) {
            int rl = it * 16 + r_base;
            int cg = c ^ (rl & 15);
            int rg = row0 + rl; if (rg >= M) rg = M - 1;
            const u16* gp = A + (long long)rg * D + cg * 8;
            __builtin_amdgcn_global_load_lds(
                (const __attribute__((address_space(1))) void*)gp,
                (__attribute__((address_space(3))) void*)(lds0 + it * 4096 + wv * 1024),
                16, 0, 0);
        }
    }

    // paired-col B frags: frag nt holds actual col wv*32 + 2*l16 + nt at slot n=l16
    s16x8 bf[4][2];
#pragma unroll
    for (int kk = 0; kk < 4; ++kk)
#pragma unroll
        for (int j = 0; j < 8; ++j) {
            u32 p = *(const u32*)(B + (kk * 32 + quad * 8 + j) * D + wv * 32 + 2 * l16);
            bf[kk][0][j] = (short)(p & 0xffffu);
            bf[kk][1][j] = (short)(p >> 16);
        }

    f32x4 acc[8][2];
#pragma unroll
    for (int mt = 0; mt < 8; ++mt) { acc[mt][0] = (f32x4)0.f; acc[mt][1] = (f32x4)0.f; }

    __syncthreads();

#pragma unroll
    for (int kk = 0; kk < 4; ++kk) {
        const int chunk = (kk * 4 + quad) ^ l16;
#pragma unroll
        for (int mt = 0; mt < 8; ++mt) {
            int rl = mt * 16 + l16;
            s16x8 a = *(const s16x8*)(As + rl * D + chunk * 8);
            acc[mt][0] = __builtin_amdgcn_mfma_f32_16x16x32_bf16(a, bf[kk][0], acc[mt][0], 0, 0, 0);
            acc[mt][1] = __builtin_amdgcn_mfma_f32_16x16x32_bf16(a, bf[kk][1], acc[mt][1], 0, 0, 0);
        }
    }

    // ---- epilogue: stage C in LDS (16B-chunk XOR swizzle), stream full lines ----
    float b0 = 0.f, b1 = 0.f;
    if (y == R_) {
        b0 = bf2f(bias[wv * 32 + 2 * l16]);
        b1 = bf2f(bias[wv * 32 + 2 * l16 + 1]);
    }
    __syncthreads();                 // all MFMA ds_reads of As complete
    u32* Cs = (u32*)As;              // [128 rows][64 u32]
    const int cpair = wv * 16 + l16;
    const int chunkc = cpair >> 2, sub = cpair & 3;
#pragma unroll
    for (int mt = 0; mt < 8; ++mt)
#pragma unroll
        for (int i = 0; i < 4; ++i) {
            int rl = mt * 16 + quad * 4 + i;
            Cs[rl * 64 + (((chunkc ^ (rl & 15)) << 2) | sub)] =
                pack_bf2(acc[mt][0][i] + b0, acc[mt][1][i] + b1);
        }
    __syncthreads();
    u32* o = (y < R_) ? ((u32*)xw + (long long)y * ((long long)M * 64)) : (u32*)sl;
#pragma unroll
    for (int it = 0; it < 8; ++it) {
        int r_loc = wv * 32 + it * 4 + (lane >> 4);
        int c  = lane & 15;
        int cs = c ^ (r_loc & 15);
        u32x4 v = *(const u32x4*)&Cs[r_loc * 64 + cs * 4];
        int rg = row0 + r_loc;
        if (rg < M) *(u32x4*)&o[(long long)rg * 64 + c * 4] = v;
    }
}

// ---- aggregate v2 (R7-proven): one wave per dst node; half-wave per edge row ----
__global__ __launch_bounds__(256)
void aggregate(const u16* __restrict__ xw, const u16* __restrict__ sl,
               const int* __restrict__ offs, const int* __restrict__ rowidx,
               void* __restrict__ out, int N, int mode, const int* __restrict__ flag)
{
    int node = blockIdx.x * 4 + (threadIdx.x >> 6);
    int lane = threadIdx.x & 63;
    int p  = lane & 31;
    int hi = lane >> 5;
    if (node >= N) return;
    const u32x2* xw2 = (const u32x2*)xw;   // row stride = 32 u32x2

    float a0, a1, a2, a3;
    if (hi == 0) {
        u32x2 s2 = ((const u32x2*)sl)[(long long)node * 32 + p];
        unpack2(s2[0], a0, a1);
        unpack2(s2[1], a2, a3);
    } else { a0 = a1 = a2 = a3 = 0.f; }

    int j = offs[node], j1 = offs[node + 1];
    for (; j + 8 <= j1; j += 8) {
        int r0 = rowidx[j + 0 + hi];
        int r1 = rowidx[j + 2 + hi];
        int r2 = rowidx[j + 4 + hi];
        int r3 = rowidx[j + 6 + hi];
        u32x2 u0 = xw2[(long long)r0 * 32 + p];
        u32x2 u1 = xw2[(long long)r1 * 32 + p];
        u32x2 u2 = xw2[(long long)r2 * 32 + p];
        u32x2 u3 = xw2[(long long)r3 * 32 + p];
        float l, h;
        unpack2(u0[0], l, h); a0 += l; a1 += h;  unpack2(u0[1], l, h); a2 += l; a3 += h;
        unpack2(u1[0], l, h); a0 += l; a1 += h;  unpack2(u1[1], l, h); a2 += l; a3 += h;
        unpack2(u2[0], l, h); a0 += l; a1 += h;  unpack2(u2[1], l, h); a2 += l; a3 += h;
        unpack2(u3[0], l, h); a0 += l; a1 += h;  unpack2(u3[1], l, h); a2 += l; a3 += h;
    }
    for (; j < j1; j += 2) {
        bool ok = (j + hi < j1);
        int rr = rowidx[ok ? j + hi : j];
        u32x2 u = xw2[(long long)rr * 32 + p];
        if (!ok) { u[0] = 0; u[1] = 0; }
        float l, h;
        unpack2(u[0], l, h); a0 += l; a1 += h;
        unpack2(u[1], l, h); a2 += l; a3 += h;
    }

    a0 += __shfl_xor(a0, 32, 64);
    a1 += __shfl_xor(a1, 32, 64);
    a2 += __shfl_xor(a2, 32, 64);
    a3 += __shfl_xor(a3, 32, 64);

    if (mode == 0) {
        if (hi == 0) {
            u32x2 w;
            w[0] = pack_bf2(fmaxf(a0, 0.f), fmaxf(a1, 0.f));
            w[1] = pack_bf2(fmaxf(a2, 0.f), fmaxf(a3, 0.f));
            ((u32x2*)out)[(long long)node * 32 + p] = w;
        }
    } else {
        float s = a0 * a0 + a1 * a1 + a2 * a2 + a3 * a3;
#pragma unroll
        for (int off = 16; off > 0; off >>= 1) s += __shfl_xor(s, off, 64);
        float sc = 1.f / fmaxf(sqrtf(s), 1e-12f);
        if (hi == 0) {
            if (*flag) {
                f32x4 w; w[0] = a0 * sc; w[1] = a1 * sc; w[2] = a2 * sc; w[3] = a3 * sc;
                ((f32x4*)out)[(long long)node * 32 + p] = w;
            } else {
                u32x2 w;
                w[0] = pack_bf2(a0 * sc, a1 * sc);
                w[1] = pack_bf2(a2 * sc, a3 * sc);
                ((u32x2*)out)[(long long)node * 32 + p] = w;
            }
        }
    }
}

static inline size_t align256(size_t x) { return (x + 255) & ~(size_t)255; }

extern "C" void kernel_launch(void* const* d_in, const int* in_sizes, int n_in,
                              void* d_out, int out_size, void* d_ws, size_t ws_size,
                              hipStream_t stream)
{
    const void* x_in   = d_in[0];
    const void* W1_in  = d_in[1];
    const void* lW1_in = d_in[2];
    const void* b1_in  = d_in[3];
    const void* W2_in  = d_in[4];
    const void* lW2_in = d_in[5];
    const void* b2_in  = d_in[6];
    const int* src = (const int*)d_in[7];
    const int* dst = (const int*)d_in[8];
    const int* et  = (const int*)d_in[9];

    const int N = in_sizes[0] / D;            // 50000
    const int E = in_sizes[7];                // 800000
    const int R = in_sizes[1] / (D * D);      // 8
    const int nbuck = (N + 255) >> 8;         // 196

    const long long ND  = (long long)N * D;
    const long long RDD = (long long)R * D * D;
    const long long DDl = (long long)D * D;

    size_t off = 0;
    auto alloc = [&](size_t bytes) { size_t o = off; off = align256(off + bytes); return o; };
    size_t o_flag = alloc(256);
    size_t o_xc   = alloc((size_t)ND * 2);
    size_t o_W1   = alloc((size_t)RDD * 2);
    size_t o_lW1  = alloc((size_t)DDl * 2);
    size_t o_b1   = alloc((size_t)D * 2);
    size_t o_W2   = alloc((size_t)RDD * 2);
    size_t o_lW2  = alloc((size_t)DDl * 2);
    size_t o_b2   = alloc((size_t)D * 2);
    size_t o_sl   = alloc((size_t)ND * 2);
    size_t o_h    = alloc((size_t)ND * 2);
    size_t o_offs = alloc((size_t)(N + 1) * 4);
    size_t o_gcnt = alloc(1024);
    size_t o_bst  = alloc(1040 * 4);
    size_t o_bcur = alloc(1024);
    size_t o_ebuf = alloc((size_t)E * 4);
    size_t o_ridx = alloc((size_t)E * 4);
    size_t o_xw   = alloc((size_t)R * ND * 2);
    (void)ws_size;

    char* ws = (char*)d_ws;
    int* flag   = (int*)(ws + o_flag);
    u16* x_c    = (u16*)(ws + o_xc);
    u16* W1c    = (u16*)(ws + o_W1);
    u16* lW1c   = (u16*)(ws + o_lW1);
    u16* b1c    = (u16*)(ws + o_b1);
    u16* W2c    = (u16*)(ws + o_W2);
    u16* lW2c   = (u16*)(ws + o_lW2);
    u16* b2c    = (u16*)(ws + o_b2);
    u16* sl     = (u16*)(ws + o_sl);
    u16* h      = (u16*)(ws + o_h);
    int* offs   = (int*)(ws + o_offs);
    int* gcnt   = (int*)(ws + o_gcnt);
    int* bstart = (int*)(ws + o_bst);
    int* bcur   = (int*)(ws + o_bcur);
    u32* ebuf   = (u32*)(ws + o_ebuf);
    int* rowidx = (int*)(ws + o_ridx);
    u16* xw     = (u16*)(ws + o_xw);

    dim3 blk(256, 1, 1);
    int mb    = (N + 127) / 128;
    int nblkE = (E + CH - 1) / CH;

    detect_dtype<<<dim3(1), blk, 0, stream>>>((const u16*)x_in, flag, gcnt, nbuck);
    to_bf16_all<<<dim3(4096), blk, 0, stream>>>(
        x_in, W1_in, lW1_in, b1_in, W2_in, lW2_in, b2_in,
        x_c, W1c, lW1c, b1c, W2c, lW2c, b2c,
        ND, RDD, DDl, (long long)D, RDD, DDl, (long long)D, flag);

    // CSR build (bucketed counting sort)
    csr_count<<<dim3(nblkE), blk, 0, stream>>>(dst, gcnt, E, nbuck);
    csr_scan<<<dim3(1), blk, 0, stream>>>(gcnt, bstart, bcur, nbuck, N, E, offs);
    csr_part<<<dim3(nblkE), blk, 0, stream>>>(src, dst, et, bcur, ebuf, E, N, nbuck);
    csr_emit<<<dim3(nbuck), blk, 0, stream>>>(ebuf, bstart, offs, rowidx, N);

    // layer 1
    gemm_k128<<<dim3(mb, R + 1), blk, 0, stream>>>(
        x_c, (const u16*)x_in, W1c, (const u16*)W1_in, lW1c, (const u16*)lW1_in,
        b1c, (const u16*)b1_in, flag, N, R, xw, sl);
    aggregate<<<dim3((N + 3) / 4), blk, 0, stream>>>(xw, sl, offs, rowidx, h, N, 0, flag);

    // layer 2
    gemm_k128<<<dim3(mb, R + 1), blk, 0, stream>>>(
        h, h, W2c, (const u16*)W2_in, lW2c, (const u16*)lW2_in,
        b2c, (const u16*)b2_in, flag, N, R, xw, sl);
    aggregate<<<dim3((N + 3) / 4), blk, 0, stream>>>(xw, sl, offs, rowidx, d_out, N, 1, flag);
}

// Round 10
// 293.245 us; speedup vs baseline: 1.1050x; 1.0420x over previous
//
#include <hip/hip_runtime.h>
#include <hip/hip_bf16.h>

#define D 128
#define CH 2048   // edges per block in CSR count/partition passes

typedef unsigned int u32;
typedef unsigned short u16;
typedef __attribute__((ext_vector_type(8))) short s16x8;
typedef __attribute__((ext_vector_type(4))) float f32x4;
typedef __attribute__((ext_vector_type(2))) float f32x2;
typedef __attribute__((ext_vector_type(2))) u32 u32x2;
typedef __attribute__((ext_vector_type(4))) u32 u32x4;

__device__ __forceinline__ float bf2f(u16 u) {
    union { u32 u; float f; } v; v.u = ((u32)u) << 16; return v.f;
}
__device__ __forceinline__ u16 f2bf(float f) {
    union { float f; u32 u; } v; v.f = f;
    return (u16)((v.u + 0x7fffu + ((v.u >> 16) & 1u)) >> 16);
}
__device__ __forceinline__ u32 pack_bf2(float a, float b) {
    __hip_bfloat162 t = __float22bfloat162_rn(make_float2(a, b));
    union { __hip_bfloat162 t; u32 u; } v; v.t = t; return v.u;
}
__device__ __forceinline__ void unpack2(u32 u, float& lo, float& hi) {
    union { u32 u; float f; } a, b;
    a.u = u << 16; b.u = u & 0xffff0000u;
    lo = a.f; hi = b.f;
}
__device__ __forceinline__ void acc8(float (&a)[8], u32x4 u) {
#pragma unroll
    for (int m = 0; m < 4; ++m) {
        float l, h;
        unpack2(u[m], l, h);
        a[2 * m] += l; a[2 * m + 1] += h;
    }
}

// per-wave dtype detection: sample 64 even-index u16s of x.
// bf16 N(0,1): ~100% sane exponents; fp32 low-half garbage: ~21%. true -> fp32.
__device__ __forceinline__ bool detect_f32(const u16* __restrict__ x) {
    int lane = threadIdx.x & 63;
    u16 u = x[2 * lane];
    int e = (u >> 7) & 0xFF;
    bool sane = (e >= 96 && e <= 150);
    unsigned long long m = __ballot(sane);
    return __popcll(m) < 32;
}

// ---- zero CSR metadata (gcnt, bcur) + offs[N]=E ----
__global__ __launch_bounds__(256)
void zero_meta(int* __restrict__ gcnt, int* __restrict__ bcur,
               int* __restrict__ offs, int N, int E) {
    int t = threadIdx.x;
    for (int k = t; k < 512; k += 256) { gcnt[k] = 0; bcur[k] = 0; }
    if (t == 0) offs[N] = E;
}

// ---- fused: blocks [0,nblkE) = per-bucket edge count; rest = bf16 convert ----
__global__ __launch_bounds__(256)
void prep(const int* __restrict__ dst, int* __restrict__ gcnt, int E, int nbuck, int nblkE,
          const void* __restrict__ s0, const void* __restrict__ s1,
          const void* __restrict__ s2, const void* __restrict__ s3,
          const void* __restrict__ s4, const void* __restrict__ s5,
          const void* __restrict__ s6,
          u16* __restrict__ d0, u16* __restrict__ d1, u16* __restrict__ d2,
          u16* __restrict__ d3, u16* __restrict__ d4, u16* __restrict__ d5,
          u16* __restrict__ d6,
          long long n0, long long n1, long long n2, long long n3,
          long long n4, long long n5, long long n6)
{
    int tid = threadIdx.x;
    if ((int)blockIdx.x < nblkE) {
        __shared__ int scnt[512];
        for (int k = tid; k < 512; k += 256) scnt[k] = 0;
        __syncthreads();
        int base = blockIdx.x * CH;
#pragma unroll
        for (int it = 0; it < CH / 256; ++it) {
            int e = base + it * 256 + tid;
            if (e < E) atomicAdd(&scnt[dst[e] >> 7], 1);
        }
        __syncthreads();
        for (int k = tid; k < nbuck; k += 256)
            if (scnt[k] > 0) atomicAdd(&gcnt[k], scnt[k]);
    } else {
        if (!detect_f32((const u16*)s0)) return;
        long long tot = n0 + n1 + n2 + n3 + n4 + n5 + n6;
        long long nconv = (long long)(gridDim.x - nblkE);
        long long stride = nconv * 256;
        for (long long i = (long long)(blockIdx.x - nblkE) * 256 + tid; i < tot; i += stride) {
            const void* s; u16* d; long long off;
            if      (i < n0)                   { s = s0; d = d0; off = i; }
            else if (i < n0+n1)                { s = s1; d = d1; off = i-n0; }
            else if (i < n0+n1+n2)             { s = s2; d = d2; off = i-n0-n1; }
            else if (i < n0+n1+n2+n3)          { s = s3; d = d3; off = i-n0-n1-n2; }
            else if (i < n0+n1+n2+n3+n4)       { s = s4; d = d4; off = i-n0-n1-n2-n3; }
            else if (i < n0+n1+n2+n3+n4+n5)    { s = s5; d = d5; off = i-n0-n1-n2-n3-n4; }
            else                               { s = s6; d = d6; off = i-n0-n1-n2-n3-n4-n5; }
            d[off] = f2bf(((const float*)s)[off]);
        }
    }
}

// ---- partition edges into bucket-contiguous ebuf; bucket = dst>>7 ----
// rec = (dst&127)<<25 | (et*N+src)   [needs R*N < 2^25]
// bucket starts computed block-locally by scanning gcnt (wave 0).
__global__ __launch_bounds__(256)
void csr_part(const int* __restrict__ src, const int* __restrict__ dst,
              const int* __restrict__ et, const int* __restrict__ gcnt,
              int* __restrict__ bcur, u32* __restrict__ ebuf, int E, int N, int nbuck) {
    __shared__ int scnt[512], sbase[512], sbstart[513];
    int tid = threadIdx.x, lane = tid & 63, wv = tid >> 6;
    for (int k = tid; k < 512; k += 256) scnt[k] = 0;
    __syncthreads();
    int base = blockIdx.x * CH;
#pragma unroll
    for (int it = 0; it < CH / 256; ++it) {
        int e = base + it * 256 + tid;
        if (e < E) atomicAdd(&scnt[dst[e] >> 7], 1);
    }
    if (wv == 0) {   // wave 0: exclusive scan of gcnt -> sbstart
        int carry = 0;
        for (int b = 0; b < nbuck; b += 64) {
            int idx = b + lane;
            int v = (idx < nbuck) ? gcnt[idx] : 0;
            int s = v;
#pragma unroll
            for (int off = 1; off < 64; off <<= 1) {
                int t = __shfl_up(s, off, 64);
                if (lane >= off) s += t;
            }
            if (idx < nbuck) sbstart[idx] = carry + s - v;
            carry += __shfl(s, 63, 64);
        }
    }
    __syncthreads();
    for (int k = tid; k < nbuck; k += 256) {
        int c = scnt[k];
        sbase[k] = c ? sbstart[k] + atomicAdd(&bcur[k], c) : 0;
    }
    __syncthreads();
    for (int k = tid; k < 512; k += 256) scnt[k] = 0;
    __syncthreads();
#pragma unroll
    for (int it = 0; it < CH / 256; ++it) {
        int e = base + it * 256 + tid;
        if (e >= E) continue;
        int d = dst[e];
        int b = d >> 7;
        int p = sbase[b] + atomicAdd(&scnt[b], 1);
        ebuf[p] = ((u32)(d & 127) << 25) | (u32)(et[e] * N + src[e]);
    }
}

// ---- one block per bucket: 128-bin dstlo counting sort -> offs + rowidx ----
__global__ __launch_bounds__(256)
void csr_emit(const u32* __restrict__ ebuf, const int* __restrict__ gcnt,
              int* __restrict__ offs, int* __restrict__ rowidx, int N) {
    __shared__ int hist[128], excl[128], cur[128];
    __shared__ int wred[4];
    int b = blockIdx.x, tid = threadIdx.x, lane = tid & 63, wv = tid >> 6;
    // lo = sum gcnt[0..b)
    int part = 0;
    for (int k = tid; k < b; k += 256) part += gcnt[k];
#pragma unroll
    for (int off = 32; off > 0; off >>= 1) part += __shfl_xor(part, off, 64);
    if (lane == 0) wred[wv] = part;
    if (tid < 128) { hist[tid] = 0; cur[tid] = 0; }
    __syncthreads();
    int lo = wred[0] + wred[1] + wred[2] + wred[3];
    int hi = lo + gcnt[b];
    for (int i = lo + tid; i < hi; i += 256) atomicAdd(&hist[ebuf[i] >> 25], 1);
    __syncthreads();
    if (wv == 0) {   // scan 128 bins
        int carry = 0;
#pragma unroll
        for (int c = 0; c < 2; ++c) {
            int idx = c * 64 + lane;
            int v = hist[idx];
            int s = v;
#pragma unroll
            for (int off = 1; off < 64; off <<= 1) {
                int t = __shfl_up(s, off, 64);
                if (lane >= off) s += t;
            }
            excl[idx] = carry + s - v;
            carry += __shfl(s, 63, 64);
        }
    }
    __syncthreads();
    if (tid < 128) {
        int node = (b << 7) + tid;
        if (node < N) offs[node] = lo + excl[tid];
    }
    __syncthreads();
    for (int i = lo + tid; i < hi; i += 256) {
        u32 rec = ebuf[i];
        int key = rec >> 25;
        int p = lo + excl[key] + atomicAdd(&cur[key], 1);
        rowidx[p] = (int)(rec & 0x1FFFFFFu);
    }
}

// ---- GEMM: C[M,128] = A @ B ; LDS-staged A; LDS-transposed full-line epilogue ----
__global__ __launch_bounds__(256)
void gemm_k128(const u16* __restrict__ xdet,
               const u16* __restrict__ Ac, const u16* __restrict__ Ao,
               const u16* __restrict__ Wc, const u16* __restrict__ Wo,
               const u16* __restrict__ lWc, const u16* __restrict__ lWo,
               const u16* __restrict__ bc, const u16* __restrict__ bo,
               int M, int R_, u16* __restrict__ xw, u16* __restrict__ sl)
{
    __shared__ u16 As[128 * 128];    // 32 KB; reused as C staging
    const bool f = detect_f32(xdet);
    const u16* A     = f ? Ac  : Ao;
    const u16* Wall  = f ? Wc  : Wo;
    const u16* loopW = f ? lWc : lWo;
    const u16* bias  = f ? bc  : bo;

    const int y = blockIdx.y;
    const u16* B = (y < R_) ? (Wall + (long long)y * D * D) : loopW;
    const int row0 = blockIdx.x * 128;
    const int tid  = threadIdx.x;
    const int lane = tid & 63;
    const int wv   = tid >> 6;
    const int quad = lane >> 4;
    const int l16  = lane & 15;

    {
        int r_base = (wv << 2) + (lane >> 4);
        int c      = lane & 15;
        auto* lds0 = (__attribute__((address_space(3))) char*)As;
#pragma unroll
        for (int it = 0; it < 8; ++it) {
            int rl = it * 16 + r_base;
            int cg = c ^ (rl & 15);
            int rg = row0 + rl; if (rg >= M) rg = M - 1;
            const u16* gp = A + (long long)rg * D + cg * 8;
            __builtin_amdgcn_global_load_lds(
                (const __attribute__((address_space(1))) void*)gp,
                (__attribute__((address_space(3))) void*)(lds0 + it * 4096 + wv * 1024),
                16, 0, 0);
        }
    }

    s16x8 bf[4][2];
#pragma unroll
    for (int kk = 0; kk < 4; ++kk)
#pragma unroll
        for (int j = 0; j < 8; ++j) {
            u32 p = *(const u32*)(B + (kk * 32 + quad * 8 + j) * D + wv * 32 + 2 * l16);
            bf[kk][0][j] = (short)(p & 0xffffu);
            bf[kk][1][j] = (short)(p >> 16);
        }

    f32x4 acc[8][2];
#pragma unroll
    for (int mt = 0; mt < 8; ++mt) { acc[mt][0] = (f32x4)0.f; acc[mt][1] = (f32x4)0.f; }

    __syncthreads();

#pragma unroll
    for (int kk = 0; kk < 4; ++kk) {
        const int chunk = (kk * 4 + quad) ^ l16;
#pragma unroll
        for (int mt = 0; mt < 8; ++mt) {
            int rl = mt * 16 + l16;
            s16x8 a = *(const s16x8*)(As + rl * D + chunk * 8);
            acc[mt][0] = __builtin_amdgcn_mfma_f32_16x16x32_bf16(a, bf[kk][0], acc[mt][0], 0, 0, 0);
            acc[mt][1] = __builtin_amdgcn_mfma_f32_16x16x32_bf16(a, bf[kk][1], acc[mt][1], 0, 0, 0);
        }
    }

    float b0 = 0.f, b1 = 0.f;
    if (y == R_) {
        b0 = bf2f(bias[wv * 32 + 2 * l16]);
        b1 = bf2f(bias[wv * 32 + 2 * l16 + 1]);
    }
    __syncthreads();
    u32* Cs = (u32*)As;
    const int cpair = wv * 16 + l16;
    const int chunkc = cpair >> 2, sub = cpair & 3;
#pragma unroll
    for (int mt = 0; mt < 8; ++mt)
#pragma unroll
        for (int i = 0; i < 4; ++i) {
            int rl = mt * 16 + quad * 4 + i;
            Cs[rl * 64 + (((chunkc ^ (rl & 15)) << 2) | sub)] =
                pack_bf2(acc[mt][0][i] + b0, acc[mt][1][i] + b1);
        }
    __syncthreads();
    u32* o = (y < R_) ? ((u32*)xw + (long long)y * ((long long)M * 64)) : (u32*)sl;
#pragma unroll
    for (int it = 0; it < 8; ++it) {
        int r_loc = wv * 32 + it * 4 + (lane >> 4);
        int c  = lane & 15;
        int cs = c ^ (r_loc & 15);
        u32x4 v = *(const u32x4*)&Cs[r_loc * 64 + cs * 4];
        int rg = row0 + r_loc;
        if (rg < M) *(u32x4*)&o[(long long)rg * 64 + c * 4] = v;
    }
}

// ---- aggregate v3: one wave per dst node; quarter-wave (16 lanes) per edge row ----
__global__ __launch_bounds__(256)
void aggregate(const u16* __restrict__ xdet,
               const u16* __restrict__ xw, const u16* __restrict__ sl,
               const int* __restrict__ offs, const int* __restrict__ rowidx,
               void* __restrict__ out, int N, int mode)
{
    int node = blockIdx.x * 4 + (threadIdx.x >> 6);
    int lane = threadIdx.x & 63;
    int p  = lane & 15;
    int qw = lane >> 4;
    if (node >= N) return;
    const u32x4* xw4 = (const u32x4*)xw;   // row stride = 16 u32x4

    float a[8];
    if (qw == 0) {
        u32x4 s4 = ((const u32x4*)sl)[(long long)node * 16 + p];
#pragma unroll
        for (int m = 0; m < 4; ++m) unpack2(s4[m], a[2 * m], a[2 * m + 1]);
    } else {
#pragma unroll
        for (int k = 0; k < 8; ++k) a[k] = 0.f;
    }

    int j = offs[node], j1 = offs[node + 1];
    for (; j + 16 <= j1; j += 16) {
        int r0 = rowidx[j + qw];
        int r1 = rowidx[j + 4 + qw];
        int r2 = rowidx[j + 8 + qw];
        int r3 = rowidx[j + 12 + qw];
        u32x4 u0 = xw4[(long long)r0 * 16 + p];
        u32x4 u1 = xw4[(long long)r1 * 16 + p];
        u32x4 u2 = xw4[(long long)r2 * 16 + p];
        u32x4 u3 = xw4[(long long)r3 * 16 + p];
        acc8(a, u0); acc8(a, u1); acc8(a, u2); acc8(a, u3);
    }
    for (; j + 4 <= j1; j += 4) {
        int r = rowidx[j + qw];
        acc8(a, xw4[(long long)r * 16 + p]);
    }
    int rem = j1 - j;
    if (rem > 0) {
        int rr = rowidx[(qw < rem) ? j + qw : j];
        u32x4 u = xw4[(long long)rr * 16 + p];
        if (qw >= rem) { u[0] = 0; u[1] = 0; u[2] = 0; u[3] = 0; }
        acc8(a, u);
    }

#pragma unroll
    for (int k = 0; k < 8; ++k) {
        a[k] += __shfl_xor(a[k], 16, 64);
        a[k] += __shfl_xor(a[k], 32, 64);
    }

    if (mode == 0) {
        if (qw == 0) {
            u32x4 w;
#pragma unroll
            for (int m = 0; m < 4; ++m)
                w[m] = pack_bf2(fmaxf(a[2 * m], 0.f), fmaxf(a[2 * m + 1], 0.f));
            ((u32x4*)out)[(long long)node * 16 + p] = w;
        }
    } else {
        float s = 0.f;
#pragma unroll
        for (int k = 0; k < 8; ++k) s += a[k] * a[k];
#pragma unroll
        for (int off = 8; off > 0; off >>= 1) s += __shfl_xor(s, off, 64);
        float sc = 1.f / fmaxf(sqrtf(s), 1e-12f);
        bool f = detect_f32(xdet);
        if (qw == 0) {
            if (f) {
                f32x4 w0, w1;
                w0[0] = a[0] * sc; w0[1] = a[1] * sc; w0[2] = a[2] * sc; w0[3] = a[3] * sc;
                w1[0] = a[4] * sc; w1[1] = a[5] * sc; w1[2] = a[6] * sc; w1[3] = a[7] * sc;
                ((f32x4*)out)[(long long)node * 32 + p * 2]     = w0;
                ((f32x4*)out)[(long long)node * 32 + p * 2 + 1] = w1;
            } else {
                u32x4 w;
#pragma unroll
                for (int m = 0; m < 4; ++m)
                    w[m] = pack_bf2(a[2 * m] * sc, a[2 * m + 1] * sc);
                ((u32x4*)out)[(long long)node * 16 + p] = w;
            }
        }
    }
}

static inline size_t align256(size_t x) { return (x + 255) & ~(size_t)255; }

extern "C" void kernel_launch(void* const* d_in, const int* in_sizes, int n_in,
                              void* d_out, int out_size, void* d_ws, size_t ws_size,
                              hipStream_t stream)
{
    const void* x_in   = d_in[0];
    const void* W1_in  = d_in[1];
    const void* lW1_in = d_in[2];
    const void* b1_in  = d_in[3];
    const void* W2_in  = d_in[4];
    const void* lW2_in = d_in[5];
    const void* b2_in  = d_in[6];
    const int* src = (const int*)d_in[7];
    const int* dst = (const int*)d_in[8];
    const int* et  = (const int*)d_in[9];

    const int N = in_sizes[0] / D;            // 50000
    const int E = in_sizes[7];                // 800000
    const int R = in_sizes[1] / (D * D);      // 8  (needs R*N < 2^25)
    const int nbuck = (N + 127) >> 7;         // 391 (<=512)

    const long long ND  = (long long)N * D;
    const long long RDD = (long long)R * D * D;
    const long long DDl = (long long)D * D;

    size_t off = 0;
    auto alloc = [&](size_t bytes) { size_t o = off; off = align256(off + bytes); return o; };
    size_t o_xc   = alloc((size_t)ND * 2);
    size_t o_W1   = alloc((size_t)RDD * 2);
    size_t o_lW1  = alloc((size_t)DDl * 2);
    size_t o_b1   = alloc((size_t)D * 2);
    size_t o_W2   = alloc((size_t)RDD * 2);
    size_t o_lW2  = alloc((size_t)DDl * 2);
    size_t o_b2   = alloc((size_t)D * 2);
    size_t o_sl   = alloc((size_t)ND * 2);
    size_t o_h    = alloc((size_t)ND * 2);
    size_t o_offs = alloc((size_t)(N + 1) * 4);
    size_t o_gcnt = alloc(512 * 4);
    size_t o_bcur = alloc(512 * 4);
    size_t o_ebuf = alloc((size_t)E * 4);
    size_t o_ridx = alloc((size_t)E * 4);
    size_t o_xw   = alloc((size_t)R * ND * 2);
    (void)ws_size;

    char* ws = (char*)d_ws;
    u16* x_c    = (u16*)(ws + o_xc);
    u16* W1c    = (u16*)(ws + o_W1);
    u16* lW1c   = (u16*)(ws + o_lW1);
    u16* b1c    = (u16*)(ws + o_b1);
    u16* W2c    = (u16*)(ws + o_W2);
    u16* lW2c   = (u16*)(ws + o_lW2);
    u16* b2c    = (u16*)(ws + o_b2);
    u16* sl     = (u16*)(ws + o_sl);
    u16* h      = (u16*)(ws + o_h);
    int* offs   = (int*)(ws + o_offs);
    int* gcnt   = (int*)(ws + o_gcnt);
    int* bcur   = (int*)(ws + o_bcur);
    u32* ebuf   = (u32*)(ws + o_ebuf);
    int* rowidx = (int*)(ws + o_ridx);
    u16* xw     = (u16*)(ws + o_xw);

    dim3 blk(256, 1, 1);
    int mb    = (N + 127) / 128;
    int nblkE = (E + CH - 1) / CH;            // 391
    const u16* xdet = (const u16*)x_in;

    zero_meta<<<dim3(1), blk, 0, stream>>>(gcnt, bcur, offs, N, E);
    prep<<<dim3(nblkE + 2048), blk, 0, stream>>>(
        dst, gcnt, E, nbuck, nblkE,
        x_in, W1_in, lW1_in, b1_in, W2_in, lW2_in, b2_in,
        x_c, W1c, lW1c, b1c, W2c, lW2c, b2c,
        ND, RDD, DDl, (long long)D, RDD, DDl, (long long)D);
    csr_part<<<dim3(nblkE), blk, 0, stream>>>(src, dst, et, gcnt, bcur, ebuf, E, N, nbuck);
    csr_emit<<<dim3(nbuck), blk, 0, stream>>>(ebuf, gcnt, offs, rowidx, N);

    // layer 1
    gemm_k128<<<dim3(mb, R + 1), blk, 0, stream>>>(
        xdet, x_c, (const u16*)x_in, W1c, (const u16*)W1_in, lW1c, (const u16*)lW1_in,
        b1c, (const u16*)b1_in, N, R, xw, sl);
    aggregate<<<dim3((N + 3) / 4), blk, 0, stream>>>(xdet, xw, sl, offs, rowidx, h, N, 0);

    // layer 2
    gemm_k128<<<dim3(mb, R + 1), blk, 0, stream>>>(
        xdet, h, h, W2c, (const u16*)W2_in, lW2c, (const u16*)lW2_in,
        b2c, (const u16*)b2_in, N, R, xw, sl);
    aggregate<<<dim3((N + 3) / 4), blk, 0, stream>>>(xdet, xw, sl, offs, rowidx, d_out, N, 1);
}